// Round 9
// baseline (9678.687 us; speedup 1.0000x reference)
//
#include <hip/hip_runtime.h>
#include <hip/hip_fp16.h>

typedef _Float16 f16x8 __attribute__((ext_vector_type(8)));
typedef float f32x4 __attribute__((ext_vector_type(4)));

namespace {
constexpr int BB = 32;    // batch
constexpr int SS = 512;   // seq len
constexpr int HH = 512;   // hidden
constexpr int G4 = 2048;  // 4*H gates
constexpr int NWGR = 32;  // workgroups per direction in recurrence (512 thr each)
constexpr int FPAD = 16;  // flag padding: 16 ints = 64B line per flag
}

// ---------------- utility kernels ----------------
__global__ void k_zero(int* __restrict__ p, int n) {
  int i = blockIdx.x * blockDim.x + threadIdx.x;
  if (i < n) p[i] = 0;
}

__global__ void k_cvt(const float* __restrict__ s, _Float16* __restrict__ d, int n) {
  int i = blockIdx.x * blockDim.x + threadIdx.x;
  int stride = gridDim.x * blockDim.x;
  for (; i < n; i += stride) d[i] = (_Float16)s[i];
}

// permuting convert for Whh: out row' = unit*4 + gate (in row = gate*512 + unit).
// A 16-row MFMA tile then spans 4 units x 4 gates, and one lane's D-frag holds
// all 4 gates of one (unit, batch) -> pointwise in registers. (R11-proven.)
__global__ void k_cvtw(const float* __restrict__ s, _Float16* __restrict__ d) {
  int i = blockIdx.x * blockDim.x + threadIdx.x;
  int stride = gridDim.x * blockDim.x;
  for (; i < G4 * HH; i += stride) {
    const int row = i >> 9, k = i & 511;
    const int u = row >> 2, g = row & 3;
    d[i] = (_Float16)s[(size_t)(g * HH + u) * HH + k];
  }
}

// ---------------- input-projection GEMM (unchanged, proven) ----------------
__global__ __launch_bounds__(256) void k_gemm(
    const _Float16* __restrict__ Ain,  // [16384][K]
    const _Float16* __restrict__ W,    // [2][2048][K]
    const float* __restrict__ bih0, const float* __restrict__ bhh0,
    const float* __restrict__ bih1, const float* __restrict__ bhh1,
    _Float16* __restrict__ gx,         // [2][512][32][2048]
    int K) {
  __shared__ _Float16 As[128][40];
  __shared__ _Float16 Bs[128][40];
  const int tid = threadIdx.x;
  const int lane = tid & 63, wave = tid >> 6;
  const int dir = blockIdx.z;
  const int r0 = blockIdx.x * 128;
  const int n0 = blockIdx.y * 128;
  const _Float16* Wd = W + (size_t)dir * G4 * K;
  const float* bi = dir ? bih1 : bih0;
  const float* bh = dir ? bhh1 : bhh0;
  const int mw = wave & 1, nw = wave >> 1;

  f32x4 acc[4][4];
#pragma unroll
  for (int a = 0; a < 4; ++a)
#pragma unroll
    for (int b = 0; b < 4; ++b) acc[a][b] = (f32x4){0.f, 0.f, 0.f, 0.f};

  const int c1 = tid, c2 = tid + 256;
  const int ar1 = c1 >> 2, ak1 = (c1 & 3) * 8;
  const int ar2 = c2 >> 2, ak2 = (c2 & 3) * 8;
  const int fr = lane & 15, fq = (lane >> 4) * 8;

  const int nstage = K >> 5;
  for (int ks = 0; ks < nstage; ++ks) {
    const int k0 = ks << 5;
    *(f16x8*)&As[ar1][ak1] = *(const f16x8*)&Ain[(size_t)(r0 + ar1) * K + k0 + ak1];
    *(f16x8*)&As[ar2][ak2] = *(const f16x8*)&Ain[(size_t)(r0 + ar2) * K + k0 + ak2];
    *(f16x8*)&Bs[ar1][ak1] = *(const f16x8*)&Wd[(size_t)(n0 + ar1) * K + k0 + ak1];
    *(f16x8*)&Bs[ar2][ak2] = *(const f16x8*)&Wd[(size_t)(n0 + ar2) * K + k0 + ak2];
    __syncthreads();
    f16x8 af[4], bf[4];
#pragma unroll
    for (int mt = 0; mt < 4; ++mt) af[mt] = *(const f16x8*)&As[mw * 64 + mt * 16 + fr][fq];
#pragma unroll
    for (int nt = 0; nt < 4; ++nt) bf[nt] = *(const f16x8*)&Bs[nw * 64 + nt * 16 + fr][fq];
#pragma unroll
    for (int mt = 0; mt < 4; ++mt)
#pragma unroll
      for (int nt = 0; nt < 4; ++nt)
        acc[mt][nt] = __builtin_amdgcn_mfma_f32_16x16x32_f16(af[mt], bf[nt], acc[mt][nt], 0, 0, 0);
    __syncthreads();
  }

  const int q4 = (lane >> 4) * 4;
#pragma unroll
  for (int nt = 0; nt < 4; ++nt) {
    const int col = n0 + nw * 64 + nt * 16 + fr;
    const float bsum = bi[col] + bh[col];
#pragma unroll
    for (int mt = 0; mt < 4; ++mt) {
#pragma unroll
      for (int q = 0; q < 4; ++q) {
        const int r = r0 + mw * 64 + mt * 16 + q4 + q;
        const int b = r >> 9, t = r & 511;
        gx[(((size_t)dir * SS + t) * BB + b) * G4 + col] = (_Float16)(acc[mt][nt][q] + bsum);
      }
    }
  }
}

// ---------------- fast activations ----------------
__device__ __forceinline__ float sigmoid_fast(float x) {
  return __fdividef(1.f, 1.f + __expf(-x));
}
__device__ __forceinline__ float tanh_fast(float x) {
  const float e = __expf(2.f * x);
  return 1.f - __fdividef(2.f, e + 1.f);
}

// ---------------- recurrence: 64 WGs = 32 x 512thr per direction ----------------
// R13 = R12's partition + protocol with the LDS pipeline deleted.
// Wave = (batch-half m, unit-quad uq) computes FULL K=512 for its 4 units via
// 16 MFMAs; A = unit-major-permuted Whh' (k_cvtw, R11-proven mapping), so one
// lane's 4 accs = all 4 gates of (unit wg*16+uq*4+qd, batch m*16+c). Pointwise
// runs straight from MFMA output: no gp_s scatter, no B2 barrier, no LDS
// reduce, no bank conflicts (16.8M/dispatch removed from the serial chain).
// Costs: h loads 4->16 x16B/lane (same 64B/row coalescing as R4, pipelined);
// the 4 uq-waves duplicate h reads (merged in L2/LLC; one-shot, not polled).
// Protocol unchanged from R12: y as exchange, agent-scope quad stores, release
// fence + B4 drain + tid0 per-WG flag; single poller wave (now 32 lines, since
// full-K fan-in = 32 -- but B2 already coupled the WG to all 32 producers, so
// effective skew coupling is identical); other waves LDS-spin on done_s.
__global__ __launch_bounds__(512, 1) void k_recur(
    const _Float16* __restrict__ gx,   // [2][512][32][2048]
    const _Float16* __restrict__ Wp,   // [2][2048][512] unit-major permuted, this layer
    _Float16* __restrict__ y,          // [32][512][1024] fp16 layer output (exchange)
    float* __restrict__ outf,          // nullptr, or [32][512][1024] fp32 (layer 1)
    int* __restrict__ flags) {         // [2][NWGR*FPAD]
  const int tid = threadIdx.x;
  const int lane = tid & 63, wave = tid >> 6;   // wave 0..7
  const int wg = blockIdx.x & (NWGR - 1);
  const int dir = blockIdx.x >> 5;
  const int m = wave >> 2, uq = wave & 3;       // batch half, unit quad
  const int c = lane & 15, qd = lane >> 4;

  __shared__ int done_s[16];                    // [0] used: poller broadcast

  // A-frags: W' rows wg*64 + uq*16 + c (units wg*16+uq*4+0..3 x gates 0..3),
  // k = kj*32 + qd*8  (lane k-layout matches B: both (lane>>4)*8 + j)
  const _Float16* Wpd = Wp + (size_t)dir * G4 * HH;
  f16x8 af[16];
#pragma unroll
  for (int kj = 0; kj < 16; ++kj)
    af[kj] = *(const f16x8*)&Wpd[(size_t)(wg * 64 + uq * 16 + c) * HH + kj * 32 + qd * 8];

  const int bat = m * 16 + c;          // this lane's batch
  const int ug = wg * 16 + uq * 4 + qd;  // this lane's unit
  float cstate = 0.f;

  const _Float16* gxd = gx + (size_t)dir * SS * BB * G4;
  int* fl = flags + dir * (NWGR * FPAD);

  if (tid == 0) done_s[0] = 0;
  __syncthreads();

  struct U2 { unsigned long long a, b; };

  for (int s = 0; s < SS; ++s) {
    const int t = dir ? (SS - 1 - s) : s;
    const int tprev = dir ? (t + 1) : (t - 1);

    // gx prefetch: gate q of (unit ug, batch bat); overlaps the wait
    const _Float16* gq = gxd + ((size_t)t * BB + bat) * G4 + wg * 16 + uq * 4 + qd;
    float gxv[4];
#pragma unroll
    for (int g = 0; g < 4; ++g) gxv[g] = (float)gq[g * HH];

    f32x4 acc = {0.f, 0.f, 0.f, 0.f};

    if (s > 0) {
      if (wave == 0) {
        // single poller wave: lanes 0..31 watch the direction's 32 producer flags
        while (true) {
          int v = s;
          if (lane < 32)
            v = __hip_atomic_load(&fl[lane * FPAD], __ATOMIC_RELAXED, __HIP_MEMORY_SCOPE_AGENT);
          if (__all(v >= s)) break;
          __builtin_amdgcn_s_sleep(1);
        }
        __atomic_signal_fence(__ATOMIC_ACQUIRE);
        if (lane == 0)
          __hip_atomic_store(&done_s[0], s, __ATOMIC_RELAXED, __HIP_MEMORY_SCOPE_WORKGROUP);
      } else {
        // CU-local LDS spin (no fabric traffic)
        while (__hip_atomic_load(&done_s[0], __ATOMIC_RELAXED, __HIP_MEMORY_SCOPE_WORKGROUP) < s)
          __builtin_amdgcn_s_sleep(1);
        __atomic_signal_fence(__ATOMIC_ACQUIRE);
      }
      // B-frags: h(t-1)[batch = bat][k = kj*32 + qd*8 .. +8], full K=512.
      // Lanes c, c+16, c+32, c+48 read 64B contiguous per batch row (R4 shape).
      const unsigned long long* h64 =
          (const unsigned long long*)(y + ((size_t)bat * SS + tprev) * 1024 + dir * HH);
#pragma unroll
      for (int kj = 0; kj < 16; ++kj) {
        const int o = kj * 8 + qd * 2;
        U2 u;
        u.a = __hip_atomic_load(h64 + o, __ATOMIC_RELAXED, __HIP_MEMORY_SCOPE_AGENT);
        u.b = __hip_atomic_load(h64 + o + 1, __ATOMIC_RELAXED, __HIP_MEMORY_SCOPE_AGENT);
        const f16x8 bf = __builtin_bit_cast(f16x8, u);
        acc = __builtin_amdgcn_mfma_f32_16x16x32_f16(af[kj], bf, acc, 0, 0, 0);
      }
    }
    // pointwise straight from MFMA output: acc[q] = gate q of (unit ug, batch bat)
    const float iv = sigmoid_fast(acc[0] + gxv[0]);
    const float fv = sigmoid_fast(acc[1] + gxv[1]);
    const float gv = tanh_fast(acc[2] + gxv[2]);
    const float ov = sigmoid_fast(acc[3] + gxv[3]);
    cstate = fv * cstate + iv * gv;
    const float hv = ov * tanh_fast(cstate);

    // pack the 4 qd-lanes' units into one 8B quad (lanes c, c+16, c+32, c+48
    // hold units uq*4+0..3 of batch bat): shuffle down 16 then 32.
    const unsigned hb = (unsigned)__builtin_bit_cast(unsigned short, (_Float16)hv);
    const unsigned pair = hb | (__shfl_down(hb, 16) << 16);
    const unsigned long long quad =
        (unsigned long long)pair | ((unsigned long long)__shfl_down(pair, 32) << 32);
    if (qd == 0) {
      unsigned long long* dst = (unsigned long long*)(
          y + ((size_t)bat * SS + t) * 1024 + dir * HH + wg * 16 + uq * 4);
      __hip_atomic_store(dst, quad, __ATOMIC_RELAXED, __HIP_MEMORY_SCOPE_AGENT);
    }
    __atomic_signal_fence(__ATOMIC_RELEASE);
    __syncthreads();  // B4: every wave's h stores vmcnt-drained before the signal
    if (tid == 0)
      __hip_atomic_store(&fl[wg * FPAD], s + 1, __ATOMIC_RELAXED, __HIP_MEMORY_SCOPE_AGENT);
    // fp32 layer-1 output: after the signal, off the critical path
    if (outf) outf[((size_t)bat * SS + t) * 1024 + dir * HH + ug] = hv;
  }
}

// ---------------- launch ----------------
extern "C" void kernel_launch(void* const* d_in, const int* in_sizes, int n_in,
                              void* d_out, int out_size, void* d_ws, size_t ws_size,
                              hipStream_t stream) {
  (void)in_sizes; (void)n_in; (void)out_size; (void)ws_size;
  const float* x = (const float*)d_in[0];
  const float* Wih[4] = {(const float*)d_in[1], (const float*)d_in[5],
                         (const float*)d_in[9], (const float*)d_in[13]};
  const float* Whh[4] = {(const float*)d_in[2], (const float*)d_in[6],
                         (const float*)d_in[10], (const float*)d_in[14]};
  const float* bih[4] = {(const float*)d_in[3], (const float*)d_in[7],
                         (const float*)d_in[11], (const float*)d_in[15]};
  const float* bhh[4] = {(const float*)d_in[4], (const float*)d_in[8],
                         (const float*)d_in[12], (const float*)d_in[16]};

  char* p = (char*)d_ws;
  auto take = [&](size_t bytes) { char* r = p; p += (bytes + 255) & ~(size_t)255; return r; };
  _Float16* x16  = (_Float16*)take((size_t)BB * SS * 512 * 2);
  _Float16* wih0 = (_Float16*)take((size_t)2 * G4 * 512 * 2);
  _Float16* wih1 = (_Float16*)take((size_t)2 * G4 * 1024 * 2);
  _Float16* whhp = (_Float16*)take((size_t)4 * G4 * HH * 2);   // unit-major permuted
  _Float16* gx   = (_Float16*)take((size_t)2 * SS * BB * G4 * 2);
  _Float16* y0   = (_Float16*)take((size_t)BB * SS * 1024 * 2);
  _Float16* y1   = (_Float16*)take((size_t)BB * SS * 1024 * 2);
  int* flags     = (int*)take((size_t)2 * 2 * NWGR * FPAD * 4);  // 2 layers x 2 dirs

  hipLaunchKernelGGL(k_zero, dim3(8), dim3(256), 0, stream, flags, 2 * 2 * NWGR * FPAD);
  hipLaunchKernelGGL(k_cvt, dim3(512), dim3(256), 0, stream, x, x16, BB * SS * 512);
  hipLaunchKernelGGL(k_cvt, dim3(128), dim3(256), 0, stream, Wih[0], wih0, G4 * 512);
  hipLaunchKernelGGL(k_cvt, dim3(128), dim3(256), 0, stream, Wih[1], wih0 + (size_t)G4 * 512, G4 * 512);
  hipLaunchKernelGGL(k_cvt, dim3(256), dim3(256), 0, stream, Wih[2], wih1, G4 * 1024);
  hipLaunchKernelGGL(k_cvt, dim3(256), dim3(256), 0, stream, Wih[3], wih1 + (size_t)G4 * 1024, G4 * 1024);
  for (int i = 0; i < 4; ++i)
    hipLaunchKernelGGL(k_cvtw, dim3(512), dim3(256), 0, stream, Whh[i],
                       whhp + (size_t)i * G4 * HH);

  // layer 0
  hipLaunchKernelGGL(k_gemm, dim3(128, 16, 2), dim3(256), 0, stream,
                     x16, wih0, bih[0], bhh[0], bih[1], bhh[1], gx, 512);
  {
    const _Float16* gxp = gx; const _Float16* wpp = whhp;
    _Float16* yp = y0; float* op = nullptr; int* cp = flags;
    void* args[] = {&gxp, &wpp, &yp, &op, &cp};
    hipLaunchCooperativeKernel((const void*)k_recur, dim3(2 * NWGR), dim3(512), args, 0, stream);
  }
  // layer 1
  hipLaunchKernelGGL(k_gemm, dim3(128, 16, 2), dim3(256), 0, stream,
                     y0, wih1, bih[2], bhh[2], bih[3], bhh[3], gx, 1024);
  {
    const _Float16* gxp = gx; const _Float16* wpp = whhp + (size_t)2 * G4 * HH;
    _Float16* yp = y1; float* op = (float*)d_out; int* cp = flags + 2 * NWGR * FPAD;
    void* args[] = {&gxp, &wpp, &yp, &op, &cp};
    hipLaunchCooperativeKernel((const void*)k_recur, dim3(2 * NWGR), dim3(512), args, 0, stream);
  }
}

// Round 10
// 3218.841 us; speedup vs baseline: 3.0069x; 3.0069x over previous
//
#include <hip/hip_runtime.h>
#include <hip/hip_fp16.h>

typedef _Float16 f16x8 __attribute__((ext_vector_type(8)));
typedef float f32x4 __attribute__((ext_vector_type(4)));

namespace {
constexpr int BB = 32;    // batch
constexpr int SS = 512;   // seq len
constexpr int HH = 512;   // hidden
constexpr int G4 = 2048;  // 4*H gates
constexpr int NWGR = 32;  // workgroups per direction in recurrence (512 thr each)
constexpr int FPAD = 16;  // flag padding: 16 ints = 64B line per flag
}

// ---------------- utility kernels ----------------
__global__ void k_zero(int* __restrict__ p, int n) {
  int i = blockIdx.x * blockDim.x + threadIdx.x;
  if (i < n) p[i] = 0;
}

// consolidated fp32->fp16 convert: 9 segments in one launch (was 7 launches)
struct CvtSeg { const float* s; _Float16* d; int n; };
struct CvtArgs { CvtSeg seg[9]; };
__global__ void k_cvt9(CvtArgs a) {
  const CvtSeg sg = a.seg[blockIdx.y];
  int i = blockIdx.x * blockDim.x + threadIdx.x;
  const int stride = gridDim.x * blockDim.x;
  for (; i < sg.n; i += stride) sg.d[i] = (_Float16)sg.s[i];
}

// ---------------- input-projection GEMM (unchanged, proven) ----------------
__global__ __launch_bounds__(256) void k_gemm(
    const _Float16* __restrict__ Ain,  // [16384][K]
    const _Float16* __restrict__ W,    // [2][2048][K]
    const float* __restrict__ bih0, const float* __restrict__ bhh0,
    const float* __restrict__ bih1, const float* __restrict__ bhh1,
    _Float16* __restrict__ gx,         // [2][512][32][2048]
    int K) {
  __shared__ _Float16 As[128][40];
  __shared__ _Float16 Bs[128][40];
  const int tid = threadIdx.x;
  const int lane = tid & 63, wave = tid >> 6;
  const int dir = blockIdx.z;
  const int r0 = blockIdx.x * 128;
  const int n0 = blockIdx.y * 128;
  const _Float16* Wd = W + (size_t)dir * G4 * K;
  const float* bi = dir ? bih1 : bih0;
  const float* bh = dir ? bhh1 : bhh0;
  const int mw = wave & 1, nw = wave >> 1;

  f32x4 acc[4][4];
#pragma unroll
  for (int a = 0; a < 4; ++a)
#pragma unroll
    for (int b = 0; b < 4; ++b) acc[a][b] = (f32x4){0.f, 0.f, 0.f, 0.f};

  const int c1 = tid, c2 = tid + 256;
  const int ar1 = c1 >> 2, ak1 = (c1 & 3) * 8;
  const int ar2 = c2 >> 2, ak2 = (c2 & 3) * 8;
  const int fr = lane & 15, fq = (lane >> 4) * 8;

  const int nstage = K >> 5;
  for (int ks = 0; ks < nstage; ++ks) {
    const int k0 = ks << 5;
    *(f16x8*)&As[ar1][ak1] = *(const f16x8*)&Ain[(size_t)(r0 + ar1) * K + k0 + ak1];
    *(f16x8*)&As[ar2][ak2] = *(const f16x8*)&Ain[(size_t)(r0 + ar2) * K + k0 + ak2];
    *(f16x8*)&Bs[ar1][ak1] = *(const f16x8*)&Wd[(size_t)(n0 + ar1) * K + k0 + ak1];
    *(f16x8*)&Bs[ar2][ak2] = *(const f16x8*)&Wd[(size_t)(n0 + ar2) * K + k0 + ak2];
    __syncthreads();
    f16x8 af[4], bf[4];
#pragma unroll
    for (int mt = 0; mt < 4; ++mt) af[mt] = *(const f16x8*)&As[mw * 64 + mt * 16 + fr][fq];
#pragma unroll
    for (int nt = 0; nt < 4; ++nt) bf[nt] = *(const f16x8*)&Bs[nw * 64 + nt * 16 + fr][fq];
#pragma unroll
    for (int mt = 0; mt < 4; ++mt)
#pragma unroll
      for (int nt = 0; nt < 4; ++nt)
        acc[mt][nt] = __builtin_amdgcn_mfma_f32_16x16x32_f16(af[mt], bf[nt], acc[mt][nt], 0, 0, 0);
    __syncthreads();
  }

  const int q4 = (lane >> 4) * 4;
#pragma unroll
  for (int nt = 0; nt < 4; ++nt) {
    const int col = n0 + nw * 64 + nt * 16 + fr;
    const float bsum = bi[col] + bh[col];
#pragma unroll
    for (int mt = 0; mt < 4; ++mt) {
#pragma unroll
      for (int q = 0; q < 4; ++q) {
        const int r = r0 + mw * 64 + mt * 16 + q4 + q;
        const int b = r >> 9, t = r & 511;
        gx[(((size_t)dir * SS + t) * BB + b) * G4 + col] = (_Float16)(acc[mt][nt][q] + bsum);
      }
    }
  }
}

// ---------------- fast activations ----------------
__device__ __forceinline__ float sigmoid_fast(float x) {
  return __fdividef(1.f, 1.f + __expf(-x));
}
__device__ __forceinline__ float tanh_fast(float x) {
  const float e = __expf(2.f * x);
  return 1.f - __fdividef(2.f, e + 1.f);
}

// ---------------- recurrence: 64 WGs = 32 x 512thr per direction ----------------
// R14 = R12 (best measured: 1808us/dispatch) with ONE mechanism change:
// consumer h-loads switch from agent-scope atomics (LLC every time, ~1200cy,
// R13 proved this is the expensive term) to PLAIN f16x8 loads (L1/L2-cacheable).
// Correctness argument:
//  * producers' h stores stay AGENT-scope -> always land at the LLC.
//  * kernel-dispatch acquire invalidates L1/L2 (standard HSA; it's why our
//    cross-kernel gx dataflow with plain stores has always been correct), so
//    no stale pre-launch copies exist.
//  * within the launch, each y[bat][t] line is demand-fetched only AFTER the
//    flag for step t is detected (post-LLC-landing); CDNA caches are
//    demand-fill, so the first L2/L1 fill per XCD is fresh, later hits are of
//    that fresh copy. The existing acquire signal-fence blocks compiler
//    hoisting; in-order waves block HW hoisting past the poll branch.
// Win: all 32 WGs/dir read the SAME 32KB of h per step; first toucher per XCD
// pays LLC, the rest hit L2 (~300cy) -> one of the 4 coherent RTs in the step
// chain largely disappears. Everything else byte-for-byte R12 (poller-split
// flag detect, LDS partial reduce, B2/B4 barriers, per-WG flag signal).
__global__ __launch_bounds__(512, 1) void k_recur(
    const _Float16* __restrict__ gx,   // [2][512][32][2048]
    const _Float16* __restrict__ Whh,  // [2][2048][512] fp16, this layer
    _Float16* __restrict__ y,          // [32][512][1024] fp16 layer output
    float* __restrict__ outf,          // nullptr, or [32][512][1024] fp32 (layer 1)
    int* __restrict__ flags) {         // [2][NWGR*FPAD]
  const int tid = threadIdx.x;
  const int lane = tid & 63, wave = tid >> 6;   // wave 0..7
  const int wg = blockIdx.x & (NWGR - 1);
  const int dir = blockIdx.x >> 5;
  const int m = wave & 1, kc = wave >> 1;       // batch half, K chunk

  __shared__ float gp_s[16][32][18];            // [kc*4+gate][batch][unit] partials
  __shared__ int done_s[4];                     // per-kc detected step (LDS broadcast)

  const int c = lane & 15;
  const int qd = lane >> 4;
  const int quad8 = qd * 8;

  // B-frags: gate row = g*512 + wg*16 + c, k = kc*128 + kj*32 + quad8
  const _Float16* WdB = Whh + (size_t)dir * G4 * HH;
  f16x8 bfrag[4][4];
#pragma unroll
  for (int g = 0; g < 4; ++g)
#pragma unroll
    for (int kj = 0; kj < 4; ++kj)
      bfrag[g][kj] =
          *(const f16x8*)&WdB[(size_t)(g * HH + wg * 16 + c) * HH + kc * 128 + kj * 32 + quad8];

  const int tb = tid >> 4, tu = tid & 15;  // pointwise ownership (batch, unit)
  float cstate = 0.f;

  const _Float16* gxd = gx + (size_t)dir * SS * BB * G4;
  int* fl = flags + dir * (NWGR * FPAD);
  // this wave's K-chunk [kc*128, kc*128+128) is produced by WGs kc*8 .. kc*8+7
  const int myprod = kc * 8 + (lane & 7);

  if (tid < 4) done_s[tid] = 0;
  __syncthreads();

  for (int s = 0; s < SS; ++s) {
    const int t = dir ? (SS - 1 - s) : s;
    const int tprev = dir ? (t + 1) : (t - 1);

    // gx prefetch (plain cached loads; overlaps the wait)
    const _Float16* gq = gxd + ((size_t)t * BB + tb) * G4 + wg * 16 + tu;
    const float gxi = (float)gq[0];
    const float gxf = (float)gq[HH];
    const float gxg = (float)gq[2 * HH];
    const float gxo = (float)gq[3 * HH];

    f32x4 acc[4];
#pragma unroll
    for (int g = 0; g < 4; ++g) acc[g] = (f32x4){0.f, 0.f, 0.f, 0.f};

    if (s > 0) {
      if (m == 0) {
        // poller wave for this kc: lanes 0..7 each watch one of the 8 producers
        while (true) {
          int v = s;
          if (lane < 8)
            v = __hip_atomic_load(&fl[myprod * FPAD], __ATOMIC_RELAXED, __HIP_MEMORY_SCOPE_AGENT);
          if (__all(v >= s)) break;
          __builtin_amdgcn_s_sleep(1);
        }
        __atomic_signal_fence(__ATOMIC_ACQUIRE);
        if (lane == 0)
          __hip_atomic_store(&done_s[kc], s, __ATOMIC_RELAXED, __HIP_MEMORY_SCOPE_WORKGROUP);
      } else {
        // partner wave: CU-local LDS spin (no fabric traffic)
        while (__hip_atomic_load(&done_s[kc], __ATOMIC_RELAXED, __HIP_MEMORY_SCOPE_WORKGROUP) < s)
          __builtin_amdgcn_s_sleep(1);
        __atomic_signal_fence(__ATOMIC_ACQUIRE);
      }
      // A-frags: batch row = m*16 + c, this wave's disjoint 128-wide K chunk.
      // PLAIN loads (L1/L2-cacheable): see kernel comment for the freshness proof.
      const _Float16* hrow = y + ((size_t)(m * 16 + c) * SS + tprev) * 1024 + dir * HH;
      f16x8 af[4];
#pragma unroll
      for (int kj = 0; kj < 4; ++kj)
        af[kj] = *(const f16x8*)(hrow + kc * 128 + kj * 32 + quad8);
#pragma unroll
      for (int kj = 0; kj < 4; ++kj)
#pragma unroll
        for (int g = 0; g < 4; ++g)
          acc[g] = __builtin_amdgcn_mfma_f32_16x16x32_f16(af[kj], bfrag[g][kj], acc[g], 0, 0, 0);
    }
    // scatter partials: D col = lane&15 (unit), row = qd*4+q (batch)
#pragma unroll
    for (int g = 0; g < 4; ++g)
#pragma unroll
      for (int q = 0; q < 4; ++q) gp_s[kc * 4 + g][m * 16 + qd * 4 + q][c] = acc[g][q];
    __syncthreads();  // B2: all waves' partials in LDS

    // pointwise: thread (tb, tu) reduces 4 K-chunk partials per gate
    const float ip = gp_s[0][tb][tu] + gp_s[4][tb][tu] + gp_s[8][tb][tu] + gp_s[12][tb][tu] + gxi;
    const float fp = gp_s[1][tb][tu] + gp_s[5][tb][tu] + gp_s[9][tb][tu] + gp_s[13][tb][tu] + gxf;
    const float gp = gp_s[2][tb][tu] + gp_s[6][tb][tu] + gp_s[10][tb][tu] + gp_s[14][tb][tu] + gxg;
    const float op = gp_s[3][tb][tu] + gp_s[7][tb][tu] + gp_s[11][tb][tu] + gp_s[15][tb][tu] + gxo;
    const float iv = sigmoid_fast(ip);
    const float fv = sigmoid_fast(fp);
    const float gv = tanh_fast(gp);
    const float ov = sigmoid_fast(op);
    cstate = fv * cstate + iv * gv;
    const float hv = ov * tanh_fast(cstate);

    // pack 4 lanes' fp16 h into one 8B value via shuffles (no LDS round trip).
    // lanes l..l+3 (l%4==0) hold units tu..tu+3 of batch tb (16 | 4: no straddle).
    const unsigned hb = (unsigned)__builtin_bit_cast(unsigned short, (_Float16)hv);
    const unsigned pair = hb | (__shfl_down(hb, 1) << 16);
    const unsigned long long quad =
        (unsigned long long)pair | ((unsigned long long)__shfl_down(pair, 2) << 32);
    if ((lane & 3) == 0) {
      unsigned long long* dst =
          (unsigned long long*)(y + ((size_t)tb * SS + t) * 1024 + dir * HH + wg * 16 + tu);
      __hip_atomic_store(dst, quad, __ATOMIC_RELAXED, __HIP_MEMORY_SCOPE_AGENT);
    }
    __atomic_signal_fence(__ATOMIC_RELEASE);
    __syncthreads();  // B4: every wave's h stores vmcnt-drained before the signal
    if (tid == 0)
      __hip_atomic_store(&fl[wg * FPAD], s + 1, __ATOMIC_RELAXED, __HIP_MEMORY_SCOPE_AGENT);
    // fp32 layer-1 output: after the signal, off the critical path
    if (outf) outf[((size_t)tb * SS + t) * 1024 + dir * HH + wg * 16 + tu] = hv;
  }
}

// ---------------- launch ----------------
extern "C" void kernel_launch(void* const* d_in, const int* in_sizes, int n_in,
                              void* d_out, int out_size, void* d_ws, size_t ws_size,
                              hipStream_t stream) {
  (void)in_sizes; (void)n_in; (void)out_size; (void)ws_size;
  const float* x = (const float*)d_in[0];
  const float* Wih[4] = {(const float*)d_in[1], (const float*)d_in[5],
                         (const float*)d_in[9], (const float*)d_in[13]};
  const float* Whh[4] = {(const float*)d_in[2], (const float*)d_in[6],
                         (const float*)d_in[10], (const float*)d_in[14]};
  const float* bih[4] = {(const float*)d_in[3], (const float*)d_in[7],
                         (const float*)d_in[11], (const float*)d_in[15]};
  const float* bhh[4] = {(const float*)d_in[4], (const float*)d_in[8],
                         (const float*)d_in[12], (const float*)d_in[16]};

  char* p = (char*)d_ws;
  auto take = [&](size_t bytes) { char* r = p; p += (bytes + 255) & ~(size_t)255; return r; };
  _Float16* x16  = (_Float16*)take((size_t)BB * SS * 512 * 2);
  _Float16* wih0 = (_Float16*)take((size_t)2 * G4 * 512 * 2);
  _Float16* wih1 = (_Float16*)take((size_t)2 * G4 * 1024 * 2);
  _Float16* whh16 = (_Float16*)take((size_t)4 * G4 * 512 * 2);
  _Float16* gx   = (_Float16*)take((size_t)2 * SS * BB * G4 * 2);
  _Float16* y0   = (_Float16*)take((size_t)BB * SS * 1024 * 2);
  _Float16* y1   = (_Float16*)take((size_t)BB * SS * 1024 * 2);
  int* flags     = (int*)take((size_t)2 * 2 * NWGR * FPAD * 4);  // 2 layers x 2 dirs

  hipLaunchKernelGGL(k_zero, dim3(8), dim3(256), 0, stream, flags, 2 * 2 * NWGR * FPAD);

  // one consolidated convert launch (was 7)
  CvtArgs ca;
  ca.seg[0] = {x,      x16,  BB * SS * 512};
  ca.seg[1] = {Wih[0], wih0, G4 * 512};
  ca.seg[2] = {Wih[1], wih0 + (size_t)G4 * 512, G4 * 512};
  ca.seg[3] = {Wih[2], wih1, G4 * 1024};
  ca.seg[4] = {Wih[3], wih1 + (size_t)G4 * 1024, G4 * 1024};
  ca.seg[5] = {Whh[0], whh16, G4 * 512};
  ca.seg[6] = {Whh[1], whh16 + (size_t)G4 * 512, G4 * 512};
  ca.seg[7] = {Whh[2], whh16 + (size_t)2 * G4 * 512, G4 * 512};
  ca.seg[8] = {Whh[3], whh16 + (size_t)3 * G4 * 512, G4 * 512};
  hipLaunchKernelGGL(k_cvt9, dim3(128, 9), dim3(256), 0, stream, ca);

  // layer 0
  hipLaunchKernelGGL(k_gemm, dim3(128, 16, 2), dim3(256), 0, stream,
                     x16, wih0, bih[0], bhh[0], bih[1], bhh[1], gx, 512);
  {
    const _Float16* gxp = gx; const _Float16* whhp = whh16;
    _Float16* yp = y0; float* op = nullptr; int* cp = flags;
    void* args[] = {&gxp, &whhp, &yp, &op, &cp};
    hipLaunchCooperativeKernel((const void*)k_recur, dim3(2 * NWGR), dim3(512), args, 0, stream);
  }
  // layer 1
  hipLaunchKernelGGL(k_gemm, dim3(128, 16, 2), dim3(256), 0, stream,
                     y0, wih1, bih[2], bhh[2], bih[3], bhh[3], gx, 1024);
  {
    const _Float16* gxp = gx; const _Float16* whhp = whh16 + (size_t)2 * G4 * 512;
    _Float16* yp = y1; float* op = (float*)d_out; int* cp = flags + 2 * NWGR * FPAD;
    void* args[] = {&gxp, &whhp, &yp, &op, &cp};
    hipLaunchCooperativeKernel((const void*)k_recur, dim3(2 * NWGR), dim3(512), args, 0, stream);
  }
}